// Round 1
// baseline (10551.331 us; speedup 1.0000x reference)
//
#include <hip/hip_runtime.h>
#include <hip/hip_bf16.h>

#define Bdim 128
#define Tdim 256
#define DIN 512
#define Hdim 1024
#define Sdim 128
#define DHdim 1024
#define KG 1152   // S + H (gates GEMM K)
#define KP 1536   // DIN + H (heads GEMM K)

using short8  = __attribute__((ext_vector_type(8))) short;   // 8 bf16 (4 VGPRs)
using floatx4 = __attribute__((ext_vector_type(4))) float;   // MFMA accum

#define MFMA(a, b, c) __builtin_amdgcn_mfma_f32_16x16x32_bf16((a), (b), (c), 0, 0, 0)

// ---- workspace layout (bytes). Hbuf (decoder intermediate) unions with the
// scan-phase staging (xbf/Wg/Wmv) which is dead by decoder time. Total ~78 MB.
#define HB_OFF    0ull            // 32768*1024 bf16 = 67,108,864
#define XBF_OFF   0ull            // 128*256*512 bf16 = 33,554,432 (dies before Hbuf written)
#define WG_OFF    33554432ull     // 4096*1152 bf16 = 9,437,184
#define WMV_OFF   42991616ull     // 256*1536 bf16 = 786,432
#define WD1_OFF   67108864ull     // 1024*128 bf16 = 262,144
#define WD2_OFF   67371008ull     // 512*1024 bf16 = 1,048,576
#define AB_OFF    68419584ull     // 2 x 128*1152 bf16 (ping-pong) = 589,824
#define AB_SZ     294912ull
#define ZALL_OFF  69009408ull     // 32768*128 bf16 = 8,388,608
#define CST_OFF   77398016ull     // 128*1024 f32 = 524,288
#define BIASG_OFF 77922304ull     // 4096 f32
#define BMV_OFF   77938688ull     // 256 f32
#define KL_OFF    77939712ull     // 1 f32

__device__ __forceinline__ float sigf(float v) { return 1.0f / (1.0f + __expf(-v)); }
__device__ __forceinline__ float tanhfast(float v) { return 1.0f - 2.0f / (__expf(2.0f * v) + 1.0f); }

// ---------------- prep: fp32->bf16 conversions, weight packing, state zeroing
__global__ __launch_bounds__(256) void prep_kernel(
    const float* __restrict__ x, const float* __restrict__ W_ih,
    const float* __restrict__ W_hh, const float* __restrict__ b_ih,
    const float* __restrict__ b_hh, const float* __restrict__ Wm,
    const float* __restrict__ Wv, const float* __restrict__ bm,
    const float* __restrict__ bv, const float* __restrict__ Wd1,
    const float* __restrict__ Wd2, char* __restrict__ ws) {
  long long i = (long long)blockIdx.x * 256 + threadIdx.x;
  if (i < 16777216LL) {  // x -> xbf
    ((__hip_bfloat16*)(ws + XBF_OFF))[i] = __float2bfloat16(x[i]);
    return;
  }
  i -= 16777216LL;
  if (i < 4718592LL) {  // Wg[4096][1152] = [W_ih | W_hh]
    int j = (int)(i / KG), k = (int)(i % KG);
    float v = (k < Sdim) ? W_ih[j * Sdim + k] : W_hh[(long long)j * Hdim + (k - Sdim)];
    ((__hip_bfloat16*)(ws + WG_OFF))[i] = __float2bfloat16(v);
    return;
  }
  i -= 4718592LL;
  if (i < 393216LL) {  // Wmv[256][1536] = [Wm ; Wv]
    int r = (int)(i / KP), k = (int)(i % KP);
    float v = (r < Sdim) ? Wm[r * KP + k] : Wv[(r - Sdim) * KP + k];
    ((__hip_bfloat16*)(ws + WMV_OFF))[i] = __float2bfloat16(v);
    return;
  }
  i -= 393216LL;
  if (i < 131072LL) { ((__hip_bfloat16*)(ws + WD1_OFF))[i] = __float2bfloat16(Wd1[i]); return; }
  i -= 131072LL;
  if (i < 524288LL) { ((__hip_bfloat16*)(ws + WD2_OFF))[i] = __float2bfloat16(Wd2[i]); return; }
  i -= 524288LL;
  if (i < 4096LL) { ((float*)(ws + BIASG_OFF))[i] = b_ih[i] + b_hh[i]; return; }
  i -= 4096LL;
  if (i < 256LL) { ((float*)(ws + BMV_OFF))[i] = (i < 128) ? bm[i] : bv[i - 128]; return; }
  i -= 256LL;
  if (i < 147456LL) { ((__hip_bfloat16*)(ws + AB_OFF))[i] = __float2bfloat16(0.0f); return; }  // Abuf0 = [z0|h0] = 0
  i -= 147456LL;
  if (i < 131072LL) { ((float*)(ws + CST_OFF))[i] = 0.0f; return; }  // c0 = 0
  i -= 131072LL;
  if (i == 0) { *((float*)(ws + KL_OFF)) = 0.0f; }
}

// ---------------- per-step: gates GEMM [128,1152]x[1152,4096] + LSTM cell
// grid 256: blockIdx = mblk(0..3)*64 + cg(0..63); block owns rows [32) x 16 H-cols
// (all 4 gate regions) so the LSTM elementwise is block-local via LDS.
__global__ __launch_bounds__(256) void gates_kernel(char* __restrict__ ws, int par) {
  const __hip_bfloat16* Abuf = (const __hip_bfloat16*)(ws + AB_OFF + (unsigned long long)par * AB_SZ);
  __hip_bfloat16* AbufW = (__hip_bfloat16*)(ws + AB_OFF + (unsigned long long)(par ^ 1) * AB_SZ);
  const __hip_bfloat16* Wg = (const __hip_bfloat16*)(ws + WG_OFF);
  const float* biasg = (const float*)(ws + BIASG_OFF);
  float* Cst = (float*)(ws + CST_OFF);

  __shared__ float gsm[4][32][17];  // [gate][local row][h-col], +1 pad

  int tid = threadIdx.x;
  int lane = tid & 63;
  int w = tid >> 6;          // wave 0..3
  int mblk = blockIdx.x >> 6;  // 0..3 (row block of 32)
  int cg = blockIdx.x & 63;    // 0..63 (16 H-cols)
  int mt = w & 1;              // M-tile within block
  int g0 = (w >> 1) * 2;       // gate pair {0,1} or {2,3}
  int row16 = lane & 15;
  int quad = lane >> 4;

  int arow = mblk * 32 + mt * 16 + row16;
  const __hip_bfloat16* aptr = Abuf + (size_t)arow * KG;
  const __hip_bfloat16* bptr0 = Wg + ((size_t)g0 * Hdim + cg * 16 + row16) * KG;
  const __hip_bfloat16* bptr1 = bptr0 + (size_t)Hdim * KG;

  floatx4 acc0 = {0.f, 0.f, 0.f, 0.f}, acc1 = {0.f, 0.f, 0.f, 0.f};
  #pragma unroll 4
  for (int kt = 0; kt < KG / 32; kt++) {
    int k0 = kt * 32 + quad * 8;
    short8 a = *(const short8*)(aptr + k0);
    short8 b0 = *(const short8*)(bptr0 + k0);
    short8 b1 = *(const short8*)(bptr1 + k0);
    acc0 = MFMA(a, b0, acc0);
    acc1 = MFMA(a, b1, acc1);
  }
  #pragma unroll
  for (int r = 0; r < 4; r++) {
    gsm[g0][mt * 16 + quad * 4 + r][row16] = acc0[r];
    gsm[g0 + 1][mt * 16 + quad * 4 + r][row16] = acc1[r];
  }
  __syncthreads();
  // LSTM elementwise: 32 rows x 16 cols = 512 elems
  for (int e = tid; e < 512; e += 256) {
    int rrow = e >> 4, col = e & 15;
    int gcol = cg * 16 + col;
    int grow = mblk * 32 + rrow;
    float iv = gsm[0][rrow][col] + biasg[gcol];
    float fv = gsm[1][rrow][col] + biasg[Hdim + gcol];
    float gv = gsm[2][rrow][col] + biasg[2 * Hdim + gcol];
    float ov = gsm[3][rrow][col] + biasg[3 * Hdim + gcol];
    float c_old = Cst[(size_t)grow * Hdim + gcol];
    float cn = sigf(fv) * c_old + sigf(iv) * tanhfast(gv);
    float hn = sigf(ov) * tanhfast(cn);
    Cst[(size_t)grow * Hdim + gcol] = cn;
    AbufW[(size_t)grow * KG + Sdim + gcol] = __float2bfloat16(hn);
  }
}

// ---------------- per-step: heads GEMM [128,1536]x[1536,256] + reparam + kl
// 16 blocks x 4 waves = 64 wave-tiles: mt(0..7) x st(0..7); each wave does mean+logvar.
__global__ __launch_bounds__(256) void heads_kernel(char* __restrict__ ws,
                                                    const float* __restrict__ noise, int t) {
  const __hip_bfloat16* xbf = (const __hip_bfloat16*)(ws + XBF_OFF);
  const __hip_bfloat16* Wmv = (const __hip_bfloat16*)(ws + WMV_OFF);
  const float* bmv = (const float*)(ws + BMV_OFF);
  int par = t & 1;
  __hip_bfloat16* Ab = (__hip_bfloat16*)(ws + AB_OFF + (unsigned long long)(par ^ 1) * AB_SZ);
  __hip_bfloat16* zall = (__hip_bfloat16*)(ws + ZALL_OFF);
  float* klacc = (float*)(ws + KL_OFF);

  int tid = threadIdx.x, lane = tid & 63, w = tid >> 6;
  int wg = blockIdx.x * 4 + w;  // 0..63
  int mt = wg >> 3, st = wg & 7;
  int row16 = lane & 15, quad = lane >> 4;
  int brow = mt * 16 + row16;

  const __hip_bfloat16* aptrx = xbf + ((size_t)brow * Tdim + t) * DIN;
  const __hip_bfloat16* aptrh = Ab + (size_t)brow * KG + Sdim;
  int nM = st * 16 + row16;
  const __hip_bfloat16* bpm = Wmv + (size_t)nM * KP;
  const __hip_bfloat16* bpv = Wmv + (size_t)(128 + nM) * KP;

  floatx4 am = {0.f, 0.f, 0.f, 0.f}, av = {0.f, 0.f, 0.f, 0.f};
  #pragma unroll 4
  for (int kt = 0; kt < KP / 32; kt++) {
    int k0 = kt * 32 + quad * 8;
    short8 a = (k0 < DIN) ? *(const short8*)(aptrx + k0)
                          : *(const short8*)(aptrh + (k0 - DIN));
    short8 b0 = *(const short8*)(bpm + k0);
    short8 b1 = *(const short8*)(bpv + k0);
    am = MFMA(a, b0, am);
    av = MFMA(a, b1, av);
  }
  float kls = 0.0f;
  #pragma unroll
  for (int r = 0; r < 4; r++) {
    int bb = mt * 16 + quad * 4 + r;
    int s = st * 16 + row16;
    float mean = am[r] + bmv[s];
    float lv = av[r] + bmv[128 + s];
    float std = __expf(0.5f * lv);
    float nt = noise[((size_t)bb * Tdim + t) * Sdim + s];
    float z = nt * std + mean;
    __hip_bfloat16 zb = __float2bfloat16(z);
    zall[((size_t)bb * Tdim + t) * Sdim + s] = zb;
    Ab[(size_t)bb * KG + s] = zb;
    kls += std * std + mean * mean - 0.5f * lv - 0.5f;  // log(std) = 0.5*lv exactly
  }
  for (int off = 32; off > 0; off >>= 1) kls += __shfl_down(kls, off, 64);
  if (lane == 0) atomicAdd(klacc, kls);
}

// ---------------- decoder GEMM1: Hbuf = relu(zall[32768,128] @ Wd1^T) + bd1 -> bf16
__global__ __launch_bounds__(256) void dec1_kernel(char* __restrict__ ws,
                                                   const float* __restrict__ bd1) {
  const __hip_bfloat16* zall = (const __hip_bfloat16*)(ws + ZALL_OFF);
  const __hip_bfloat16* Wd1b = (const __hip_bfloat16*)(ws + WD1_OFF);
  __hip_bfloat16* Hbuf = (__hip_bfloat16*)(ws + HB_OFF);
  int tid = threadIdx.x, lane = tid & 63, w = tid >> 6;
  int mb = blockIdx.x, nb = blockIdx.y;
  int row16 = lane & 15, quad = lane >> 4;
  int arow = mb * 64 + w * 16 + row16;
  const __hip_bfloat16* aptr = zall + (size_t)arow * Sdim;
  floatx4 acc[4] = {{0.f,0.f,0.f,0.f},{0.f,0.f,0.f,0.f},{0.f,0.f,0.f,0.f},{0.f,0.f,0.f,0.f}};
  #pragma unroll
  for (int kt = 0; kt < Sdim / 32; kt++) {
    int k0 = kt * 32 + quad * 8;
    short8 a = *(const short8*)(aptr + k0);
    #pragma unroll
    for (int j = 0; j < 4; j++) {
      const __hip_bfloat16* bp = Wd1b + (size_t)(nb * 64 + j * 16 + row16) * Sdim;
      acc[j] = MFMA(a, *(const short8*)(bp + k0), acc[j]);
    }
  }
  #pragma unroll
  for (int j = 0; j < 4; j++) {
    int n = nb * 64 + j * 16 + row16;
    float bias = bd1[n];
    #pragma unroll
    for (int r = 0; r < 4; r++) {
      int rr = mb * 64 + w * 16 + quad * 4 + r;
      float v = fmaxf(acc[j][r] + bias, 0.0f);
      Hbuf[(size_t)rr * DHdim + n] = __float2bfloat16(v);
    }
  }
}

// ---------------- decoder GEMM2: out = Hbuf[32768,1024] @ Wd2^T + bd2 -> f32
__global__ __launch_bounds__(256) void dec2_kernel(char* __restrict__ ws,
                                                   const float* __restrict__ bd2,
                                                   float* __restrict__ out) {
  const __hip_bfloat16* Hbuf = (const __hip_bfloat16*)(ws + HB_OFF);
  const __hip_bfloat16* Wd2b = (const __hip_bfloat16*)(ws + WD2_OFF);
  int tid = threadIdx.x, lane = tid & 63, w = tid >> 6;
  int mb = blockIdx.x, nb = blockIdx.y;
  int row16 = lane & 15, quad = lane >> 4;
  int arow = mb * 64 + w * 16 + row16;
  const __hip_bfloat16* aptr = Hbuf + (size_t)arow * DHdim;
  const __hip_bfloat16* bp[4];
  #pragma unroll
  for (int j = 0; j < 4; j++) bp[j] = Wd2b + (size_t)(nb * 64 + j * 16 + row16) * DHdim;
  floatx4 acc[4] = {{0.f,0.f,0.f,0.f},{0.f,0.f,0.f,0.f},{0.f,0.f,0.f,0.f},{0.f,0.f,0.f,0.f}};
  for (int kt = 0; kt < DHdim / 32; kt++) {
    int k0 = kt * 32 + quad * 8;
    short8 a = *(const short8*)(aptr + k0);
    #pragma unroll
    for (int j = 0; j < 4; j++)
      acc[j] = MFMA(a, *(const short8*)(bp[j] + k0), acc[j]);
  }
  #pragma unroll
  for (int j = 0; j < 4; j++) {
    int n = nb * 64 + j * 16 + row16;
    float bias = bd2[n];
    #pragma unroll
    for (int r = 0; r < 4; r++) {
      int rr = mb * 64 + w * 16 + quad * 4 + r;
      out[(size_t)rr * DIN + n] = acc[j][r] + bias;  // row rr = b*T+t matches [B,T,DIN]
    }
  }
}

__global__ void kl_write_kernel(const char* __restrict__ ws, float* __restrict__ out) {
  if (threadIdx.x == 0 && blockIdx.x == 0)
    out[16777216] = *(const float*)(ws + KL_OFF);
}

extern "C" void kernel_launch(void* const* d_in, const int* in_sizes, int n_in,
                              void* d_out, int out_size, void* d_ws, size_t ws_size,
                              hipStream_t stream) {
  const float* x = (const float*)d_in[0];
  const float* noise = (const float*)d_in[1];
  const float* W_ih = (const float*)d_in[2];
  const float* W_hh = (const float*)d_in[3];
  const float* b_ih = (const float*)d_in[4];
  const float* b_hh = (const float*)d_in[5];
  const float* Wm = (const float*)d_in[6];
  const float* bm = (const float*)d_in[7];
  const float* Wv = (const float*)d_in[8];
  const float* bv = (const float*)d_in[9];
  const float* Wd1 = (const float*)d_in[10];
  const float* bd1 = (const float*)d_in[11];
  const float* Wd2 = (const float*)d_in[12];
  const float* bd2 = (const float*)d_in[13];
  char* ws = (char*)d_ws;
  float* out = (float*)d_out;

  // needs ~78 MB of workspace (see layout above)
  long long total_prep = 22827265LL;
  int pblocks = (int)((total_prep + 255) / 256);
  prep_kernel<<<pblocks, 256, 0, stream>>>(x, W_ih, W_hh, b_ih, b_hh, Wm, Wv, bm, bv,
                                           Wd1, Wd2, ws);
  for (int t = 0; t < Tdim; t++) {
    gates_kernel<<<256, 256, 0, stream>>>(ws, t & 1);
    heads_kernel<<<16, 256, 0, stream>>>(ws, noise, t);
  }
  dec1_kernel<<<dim3(512, 16), 256, 0, stream>>>(ws, bd1);
  dec2_kernel<<<dim3(512, 8), 256, 0, stream>>>(ws, bd2, out);
  kl_write_kernel<<<1, 64, 0, stream>>>(ws, out);
}